// Round 16
// baseline (441.298 us; speedup 1.0000x reference)
//
#include <hip/hip_runtime.h>
#include <cstddef>
#include <cstdint>

// Problem constants
constexpr int B  = 8;
constexpr int L  = 1024;
constexpr int D  = 768;
constexpr int DI = 1536;
constexpr int DS = 16;
constexpr int NL = 2;
constexpr float DECAY   = 0.9f;
constexpr float INSCALE = 0.1f;
constexpr float LN_EPS  = 1e-5f;

typedef __attribute__((ext_vector_type(8))) short bf16x8;
typedef __attribute__((ext_vector_type(4))) float f32x4;

typedef __attribute__((address_space(3))) uint32_t       lds_u32;
typedef const __attribute__((address_space(1))) uint32_t glb_u32;

__device__ __forceinline__ float siluf(float v) { return v / (1.0f + expf(-v)); }

// f32 -> bf16 (round to nearest even)
__device__ __forceinline__ short f2bf(float f) {
  uint32_t u = __float_as_uint(f);
  u += 0x7fff + ((u >> 16) & 1);
  return (short)(u >> 16);
}
__device__ __forceinline__ float bf2f(short s) {
  return __uint_as_float(((uint32_t)(uint16_t)s) << 16);
}

__device__ __forceinline__ void load_lds16(const short* g, short* l) {
  __builtin_amdgcn_global_load_lds((glb_u32*)g, (lds_u32*)l, 16, 0, 0);
}

// ---------------- prep: x -> bf16 + weight transposes (one launch) ----------------
__global__ __launch_bounds__(256) void prep_kernel(const float* __restrict__ x,
                                                   short* __restrict__ xb,
                                                   const float* __restrict__ Wi,
                                                   const float* __restrict__ Wo,
                                                   short* __restrict__ Wt_i,
                                                   short* __restrict__ Wt_o) {
  int bid = blockIdx.x;
  if (bid < 6144) {
    int i = bid * 256 + threadIdx.x;
    float4 v = ((const float4*)x)[i];
    short4 s;
    s.x = f2bf(v.x); s.y = f2bf(v.y); s.z = f2bf(v.z); s.w = f2bf(v.w);
    ((short4*)xb)[i] = s;
    return;
  }
  bid -= 6144;
  __shared__ float t[32][33];
  const int layer = bid / 3456;
  bid %= 3456;
  const float* W; short* Wt; int K, N, bx, by;
  if (bid < 2304) {           // Wi tiles: 96 x, 24 y
    W  = Wi  + (size_t)layer * D * 2 * DI;
    Wt = Wt_i + (size_t)layer * 2 * DI * D;
    K = D; N = 2 * DI; bx = bid % 96; by = bid / 96;
  } else {                    // Wo tiles: 24 x, 48 y
    bid -= 2304;
    W  = Wo  + (size_t)layer * DI * D;
    Wt = Wt_o + (size_t)layer * D * DI;
    K = DI; N = D; bx = bid % 24; by = bid / 24;
  }
  const int n0 = bx * 32, k0 = by * 32;
  const int tx = threadIdx.x & 31, ty = threadIdx.x >> 5;
#pragma unroll
  for (int r = ty; r < 32; r += 8) t[r][tx] = W[(size_t)(k0 + r) * N + n0 + tx];
  __syncthreads();
#pragma unroll
  for (int r = ty; r < 32; r += 8) Wt[(size_t)(n0 + r) * K + k0 + tx] = f2bf(t[tx][r]);
}

// ---------------- GEMM1: 128x128 tile, 3-buffer pipeline (proven R6/R12 structure) ----
// C[M,N] = A[M,K] @ Bt[N,K]^T; split bf16 output (x_in / z halves).
__global__ __launch_bounds__(256) void gemm_bt0(const short* __restrict__ A,
                                                const short* __restrict__ Bt,
                                                short* __restrict__ Pb,
                                                int M, int N, int K) {
  __shared__ short As[3][128 * 32];
  __shared__ short Bs[3][128 * 32];
  const int tid  = threadIdx.x;
  const int lane = tid & 63;
  const int w    = tid >> 6;
  const int wm   = w >> 1;
  const int wn   = w & 1;
  const int bm   = blockIdx.y * 128;
  const int bn   = blockIdx.x * 128;

  const int seg0 = w * 2;
  const int lane16 = lane << 4;
  const int P0 = (seg0 << 10) + lane16;
  const int Q0 = P0 ^ (((P0 >> 7) & 3) << 4);
  const int row0 = Q0 >> 6;
  const int g0   = (Q0 >> 4) & 3;
  const int P1 = ((seg0 + 1) << 10) + lane16;
  const int Q1 = P1 ^ (((P1 >> 7) & 3) << 4);
  const int row1 = Q1 >> 6;
  const int g1   = (Q1 >> 4) & 3;

  const short* gA0 = A  + (size_t)(bm + row0) * K + g0 * 8;
  const short* gA1 = A  + (size_t)(bm + row1) * K + g1 * 8;
  const short* gB0 = Bt + (size_t)(bn + row0) * K + g0 * 8;
  const short* gB1 = Bt + (size_t)(bn + row1) * K + g1 * 8;

  f32x4 acc[4][4];
#pragma unroll
  for (int i = 0; i < 4; ++i)
#pragma unroll
    for (int j = 0; j < 4; ++j) acc[i][j] = (f32x4)(0.f);

  const int fr = lane & 15;
  const int h8 = (lane >> 4) << 3;
  const int NT = K / 32;

  auto stage = [&](int bi, int k0) {
    load_lds16(gA0 + k0, &As[bi][(size_t)seg0 * 512]);
    load_lds16(gA1 + k0, &As[bi][(size_t)(seg0 + 1) * 512]);
    load_lds16(gB0 + k0, &Bs[bi][(size_t)seg0 * 512]);
    load_lds16(gB1 + k0, &Bs[bi][(size_t)(seg0 + 1) * 512]);
  };
  auto compute = [&](int bi) {
    bf16x8 af[4], bfr[4];
#pragma unroll
    for (int i = 0; i < 4; ++i) {
      const int r = wm * 64 + i * 16 + fr;
      int si = (r << 5) + h8;
      si ^= ((r >> 1) & 3) << 3;
      af[i] = *(const bf16x8*)&As[bi][si];
    }
#pragma unroll
    for (int j = 0; j < 4; ++j) {
      const int r = wn * 64 + j * 16 + fr;
      int si = (r << 5) + h8;
      si ^= ((r >> 1) & 3) << 3;
      bfr[j] = *(const bf16x8*)&Bs[bi][si];
    }
#pragma unroll
    for (int i = 0; i < 4; ++i)
#pragma unroll
      for (int j = 0; j < 4; ++j)
        acc[i][j] = __builtin_amdgcn_mfma_f32_16x16x32_bf16(af[i], bfr[j], acc[i][j], 0, 0, 0);
  };

  stage(0, 0);
  stage(1, 32);
  asm volatile("s_waitcnt vmcnt(4)" ::: "memory");
  asm volatile("s_barrier" ::: "memory");

  for (int t = 0; t < NT; t += 3) {
#pragma unroll
    for (int q = 0; q < 3; ++q) {
      const int tt = t + q;
      if (tt + 2 < NT) stage((q + 2) % 3, (tt + 2) * 32);
      compute(q);
      if (tt + 1 < NT) {
        if (tt + 2 < NT) asm volatile("s_waitcnt vmcnt(4)" ::: "memory");
        else             asm volatile("s_waitcnt vmcnt(0)" ::: "memory");
        asm volatile("s_barrier" ::: "memory");
      }
    }
  }

  const int orow = (lane >> 4) * 4;
  const int ocol = lane & 15;
#pragma unroll
  for (int i = 0; i < 4; ++i) {
#pragma unroll
    for (int r = 0; r < 4; ++r) {
      const size_t row = (size_t)(bm + wm * 64 + i * 16 + orow + r);
#pragma unroll
      for (int j = 0; j < 4; ++j) {
        const int col = bn + wn * 64 + j * 16 + ocol;
        float v = acc[i][j][r];
        if (col < DI) Pb[row * DI + col] = f2bf(v);
        else          Pb[(size_t)M * DI + row * DI + col - DI] = f2bf(v);
      }
    }
  }
}

// ---------------- GEMM2: 64x128 tile, 4-buffer DEPTH-3 pipeline ----------------
// xb += y @ Wo: reads bf16 residual, accumulates in f32, writes bf16 in place.
// 4 waves; wave w owns cols [w*32,w*32+32). 4 buffers x 12 KB = 48 KB (still 3 blk/CU).
// Per step: vmcnt(6) [tiles t+1,t+2 in flight] -> barrier -> stage(t+3) -> compute(t).
// stage(t+3) overwrites tile t-1's buffer: issued after the barrier that all waves
// passed having retired their tile-(t-1) ds_reads -> safe. 3 steps of latency cover.
// Per-element K-order identical to prior variants -> bit-identical results.
__global__ __launch_bounds__(256) void gemm_bt1(const short* __restrict__ A,
                                                const short* __restrict__ Bt,
                                                short* __restrict__ Pb,
                                                int M, int N, int K) {
  __shared__ short As[4][64 * 32];    // 4 KB per buffer
  __shared__ short Bs[4][128 * 32];   // 8 KB per buffer
  const int lane = threadIdx.x & 63;
  const int w    = threadIdx.x >> 6;
  const int bm   = blockIdx.y * 64;
  const int bn   = blockIdx.x * 128;

  const int lane16 = lane << 4;
  const int PA = (w << 10) + lane16;
  const int QA = PA ^ (((PA >> 7) & 3) << 4);
  const int rowA = QA >> 6;
  const int gA_  = (QA >> 4) & 3;
  const int PB0 = ((2 * w) << 10) + lane16;
  const int QB0 = PB0 ^ (((PB0 >> 7) & 3) << 4);
  const int rowB0 = QB0 >> 6;
  const int gB0_  = (QB0 >> 4) & 3;
  const int PB1 = ((2 * w + 1) << 10) + lane16;
  const int QB1 = PB1 ^ (((PB1 >> 7) & 3) << 4);
  const int rowB1 = QB1 >> 6;
  const int gB1_  = (QB1 >> 4) & 3;

  const short* gA  = A  + (size_t)(bm + rowA) * K + gA_ * 8;
  const short* gB0 = Bt + (size_t)(bn + rowB0) * K + gB0_ * 8;
  const short* gB1 = Bt + (size_t)(bn + rowB1) * K + gB1_ * 8;

  f32x4 acc[4][2];
#pragma unroll
  for (int i = 0; i < 4; ++i)
#pragma unroll
    for (int j = 0; j < 2; ++j) acc[i][j] = (f32x4)(0.f);

  const int fr = lane & 15;
  const int h8 = (lane >> 4) << 3;
  const int NT = K / 32;    // 48 (divisible by 4)

  auto stage = [&](int bi, int k0) {
    load_lds16(gA  + k0, &As[bi][(size_t)w * 512]);
    load_lds16(gB0 + k0, &Bs[bi][(size_t)(2 * w) * 512]);
    load_lds16(gB1 + k0, &Bs[bi][(size_t)(2 * w + 1) * 512]);
  };
  auto compute = [&](int bi) {
    bf16x8 af[4], bfr[2];
#pragma unroll
    for (int i = 0; i < 4; ++i) {
      const int r = i * 16 + fr;
      int si = (r << 5) + h8;
      si ^= ((r >> 1) & 3) << 3;
      af[i] = *(const bf16x8*)&As[bi][si];
    }
#pragma unroll
    for (int j = 0; j < 2; ++j) {
      const int r = w * 32 + j * 16 + fr;
      int si = (r << 5) + h8;
      si ^= ((r >> 1) & 3) << 3;
      bfr[j] = *(const bf16x8*)&Bs[bi][si];
    }
#pragma unroll
    for (int i = 0; i < 4; ++i)
#pragma unroll
      for (int j = 0; j < 2; ++j)
        acc[i][j] = __builtin_amdgcn_mfma_f32_16x16x32_bf16(af[i], bfr[j], acc[i][j], 0, 0, 0);
  };

  // prologue: stage tiles 0,1,2 (9 loads in flight)
  stage(0, 0);
  stage(1, 32);
  stage(2, 64);

  for (int t = 0; t < NT; t += 4) {
#pragma unroll
    for (int q = 0; q < 4; ++q) {
      const int tt = t + q;
      if (tt + 2 < NT)      asm volatile("s_waitcnt vmcnt(6)" ::: "memory");
      else if (tt + 1 < NT) asm volatile("s_waitcnt vmcnt(3)" ::: "memory");
      else                  asm volatile("s_waitcnt vmcnt(0)" ::: "memory");
      asm volatile("s_barrier" ::: "memory");
      if (tt + 3 < NT) stage((tt + 3) & 3, (tt + 3) * 32);
      compute(q);
    }
  }

  const int orow = (lane >> 4) * 4;
  const int ocol = lane & 15;
#pragma unroll
  for (int i = 0; i < 4; ++i) {
#pragma unroll
    for (int r = 0; r < 4; ++r) {
      const size_t row = (size_t)(bm + i * 16 + orow + r);
#pragma unroll
      for (int j = 0; j < 2; ++j) {
        const int col = bn + w * 32 + j * 16 + ocol;
        float o = bf2f(Pb[row * N + col]) + acc[i][j][r];
        Pb[row * N + col] = f2bf(o);
      }
    }
  }
}

// ---------------- fused conv+SiLU -> partial u reduction, c-split 4-way ----------------
constexpr int CSL = DI / 4;   // 384 channels per slice
__global__ __launch_bounds__(256) void conv_u_kernel(const short* __restrict__ xin,  // [B*L, DI] bf16
                                                     const float* __restrict__ cw,   // [DI,4]
                                                     const float* __restrict__ cb,   // [DI]
                                                     const float* __restrict__ A_l,  // [L,DI,DS]
                                                     float* __restrict__ u_part) {   // [L,4,128]
  const int l = blockIdx.x;
  const int p = blockIdx.y;
  const int c_base = p * CSL;
  __shared__ float xs[B][CSL];        // 12 KB
  __shared__ float part[4][4][32];

  for (int i = threadIdx.x; i < B * (CSL / 4); i += 256) {
    const int b  = i / (CSL / 4);
    const int c4 = (i % (CSL / 4)) * 4;
    const int c  = c_base + c4;
    float4 q0 = *(const float4*)&cw[(c + 0) * 4];
    float4 q1 = *(const float4*)&cw[(c + 1) * 4];
    float4 q2 = *(const float4*)&cw[(c + 2) * 4];
    float4 q3 = *(const float4*)&cw[(c + 3) * 4];
    float4 acc = *(const float4*)&cb[c];
    const short* xp = xin + (size_t)b * L * DI + c;
#pragma unroll
    for (int k = 0; k < 4; ++k) {
      int lk = l - 3 + k;
      if (lk >= 0) {
        short4 xv = *(const short4*)&xp[(size_t)lk * DI];
        acc.x += (&q0.x)[k] * bf2f(xv.x);
        acc.y += (&q1.x)[k] * bf2f(xv.y);
        acc.z += (&q2.x)[k] * bf2f(xv.z);
        acc.w += (&q3.x)[k] * bf2f(xv.w);
      }
    }
    acc.x = siluf(acc.x); acc.y = siluf(acc.y);
    acc.z = siluf(acc.z); acc.w = siluf(acc.w);
    *(float4*)&xs[b][c4] = acc;
  }
  __syncthreads();

  const int s4 = threadIdx.x & 3;
  const int cg = threadIdx.x >> 2;   // 0..63
  const float* Ap = A_l + (size_t)l * DI * DS + s4 * 4;

  float4 acc[B];
#pragma unroll
  for (int b = 0; b < B; ++b) acc[b] = make_float4(0.f, 0.f, 0.f, 0.f);

#pragma unroll
  for (int c0 = 0; c0 < CSL; c0 += 64) {
    const int cl = c0 + cg;
    float4 a4 = *(const float4*)&Ap[(size_t)(c_base + cl) * DS];
#pragma unroll
    for (int b = 0; b < B; ++b) {
      float xv = xs[b][cl];
      acc[b].x += xv * a4.x; acc[b].y += xv * a4.y;
      acc[b].z += xv * a4.z; acc[b].w += xv * a4.w;
    }
  }

#pragma unroll
  for (int off = 32; off >= 4; off >>= 1) {
#pragma unroll
    for (int b = 0; b < B; ++b) {
      acc[b].x += __shfl_down(acc[b].x, off, 64);
      acc[b].y += __shfl_down(acc[b].y, off, 64);
      acc[b].z += __shfl_down(acc[b].z, off, 64);
      acc[b].w += __shfl_down(acc[b].w, off, 64);
    }
  }
  const int wv = threadIdx.x >> 6, lane = threadIdx.x & 63;
  if (lane < 4) {
#pragma unroll
    for (int b = 0; b < B; ++b) {
      part[wv][lane][b * 4 + 0] = acc[b].x;
      part[wv][lane][b * 4 + 1] = acc[b].y;
      part[wv][lane][b * 4 + 2] = acc[b].z;
      part[wv][lane][b * 4 + 3] = acc[b].w;
    }
  }
  __syncthreads();
  if (threadIdx.x < 128) {
    const int o  = threadIdx.x;           // b*16 + s4*4 + jj
    const int b  = o >> 4;
    const int ss = (o >> 2) & 3;
    const int jj = o & 3;
    float s = part[0][ss][b * 4 + jj] + part[1][ss][b * 4 + jj] +
              part[2][ss][b * 4 + jj] + part[3][ss][b * 4 + jj];
    u_part[((size_t)l * 4 + p) * 128 + o] = INSCALE * s;
  }
}

// ---------------- exact parallel scan (per-stream Hillis-Steele) ----------------
__global__ __launch_bounds__(256) void scan_kernel(const float* __restrict__ u_part, // [L,4,128]
                                                   float* __restrict__ hs) {         // [L,128]
  const int t = blockIdx.x;
  const int i = threadIdx.x;
  __shared__ float csc[256];

  float v[4];
#pragma unroll
  for (int j = 0; j < 4; ++j) {
    const float* up = u_part + ((size_t)(4 * i + j) * 4) * 128 + t;
    v[j] = (up[0] + up[128]) + (up[256] + up[384]);
  }
  const float p0 = v[0];
  const float p1 = p0 * DECAY + v[1];
  const float p2 = p1 * DECAY + v[2];
  const float p3 = p2 * DECAY + v[3];

  csc[i] = p3;
  __syncthreads();
  float f = DECAY * DECAY * DECAY * DECAY;   // 0.9^4
  for (int d = 1; d < 256; d <<= 1) {
    float add = (i >= d) ? csc[i - d] : 0.f;
    __syncthreads();
    csc[i] += add * f;
    __syncthreads();
    f *= f;
  }
  const float H = (i > 0) ? csc[i - 1] : 0.f;  // h_{4i-1}

  const float a1 = DECAY, a2 = DECAY * DECAY, a3 = a2 * DECAY, a4 = a2 * a2;
  float* hp = hs + (size_t)(4 * i) * 128 + t;
  hp[0]   = p0 + H * a1;
  hp[128] = p1 + H * a2;
  hp[256] = p2 + H * a3;
  hp[384] = p3 + H * a4;
}

// ---------------- xssm: y = (hs @ Bm) * silu(z), streaming ----------------
__global__ __launch_bounds__(256) void xssm_kernel(const float* __restrict__ hs,   // [L,128]
                                                   const float* __restrict__ B_l,  // [L,DS,DI]
                                                   const short* __restrict__ zb,   // [B*L,DI] bf16
                                                   short* __restrict__ y) {        // [B*L,DI] bf16
  const int l0 = blockIdx.x * 2;
  const int cb = blockIdx.y * (DI / 3);
  __shared__ float hsl[2][128];
  const int t = threadIdx.x;
  hsl[t >> 7][t & 127] = hs[(size_t)(l0 + (t >> 7)) * 128 + (t & 127)];
  __syncthreads();

  const int li = t >> 7;
  const int l  = l0 + li;
  const int c  = cb + (t & 127) * 4;
  const float* Bp = B_l + (size_t)l * DS * DI + c;

  float4 acc[B];
#pragma unroll
  for (int b = 0; b < B; ++b) acc[b] = make_float4(0.f, 0.f, 0.f, 0.f);
#pragma unroll
  for (int s = 0; s < DS; ++s) {
    float4 bv = *(const float4*)&Bp[(size_t)s * DI];
#pragma unroll
    for (int b = 0; b < B; ++b) {
      float hv = hsl[li][b * DS + s];
      acc[b].x += hv * bv.x; acc[b].y += hv * bv.y;
      acc[b].z += hv * bv.z; acc[b].w += hv * bv.w;
    }
  }
#pragma unroll
  for (int b = 0; b < B; ++b) {
    short4 zs = *(const short4*)&zb[((size_t)b * L + l) * DI + c];
    short4 o;
    o.x = f2bf(acc[b].x * siluf(bf2f(zs.x)));
    o.y = f2bf(acc[b].y * siluf(bf2f(zs.y)));
    o.z = f2bf(acc[b].z * siluf(bf2f(zs.z)));
    o.w = f2bf(acc[b].w * siluf(bf2f(zs.w)));
    *(short4*)&y[((size_t)b * L + l) * DI + c] = o;
  }
}

// ---------------- LayerNorm over D (bf16 input) ----------------
__global__ __launch_bounds__(256) void ln_kernel(const short* __restrict__ x,
                                                 const float* __restrict__ gam,
                                                 const float* __restrict__ bet,
                                                 float* __restrict__ out) {
  const int row = blockIdx.x;
  const int t = threadIdx.x;
  const short* xr = x + (size_t)row * D;
  float v0 = bf2f(xr[t]), v1 = bf2f(xr[t + 256]), v2 = bf2f(xr[t + 512]);
  float s = v0 + v1 + v2;
  __shared__ float red[4], red2[4];
  const int wid = t >> 6, lane = t & 63;
#pragma unroll
  for (int off = 32; off > 0; off >>= 1) s += __shfl_down(s, off, 64);
  if (lane == 0) red[wid] = s;
  __syncthreads();
  float mu = (red[0] + red[1] + red[2] + red[3]) * (1.0f / D);
  float d0 = v0 - mu, d1 = v1 - mu, d2 = v2 - mu;
  float q = d0 * d0 + d1 * d1 + d2 * d2;
#pragma unroll
  for (int off = 32; off > 0; off >>= 1) q += __shfl_down(q, off, 64);
  if (lane == 0) red2[wid] = q;
  __syncthreads();
  float var = (red2[0] + red2[1] + red2[2] + red2[3]) * (1.0f / D);
  float rstd = rsqrtf(var + LN_EPS);
  size_t base = (size_t)row * D;
  out[base + t]       = d0 * rstd * gam[t]       + bet[t];
  out[base + t + 256] = d1 * rstd * gam[t + 256] + bet[t + 256];
  out[base + t + 512] = d2 * rstd * gam[t + 512] + bet[t + 512];
}

extern "C" void kernel_launch(void* const* d_in, const int* in_sizes, int n_in,
                              void* d_out, int out_size, void* d_ws, size_t ws_size,
                              hipStream_t stream) {
  (void)in_sizes; (void)n_in; (void)out_size; (void)ws_size;
  const float* x   = (const float*)d_in[0];
  const float* Wi  = (const float*)d_in[1];
  const float* cw  = (const float*)d_in[2];
  const float* cb  = (const float*)d_in[3];
  const float* Wo  = (const float*)d_in[4];
  const float* gam = (const float*)d_in[5];
  const float* bet = (const float*)d_in[6];
  const float* Am  = (const float*)d_in[7];
  const float* Bm  = (const float*)d_in[8];
  float* out = (float*)d_out;

  const size_t MN = (size_t)B * L;  // 8192

  short* buf_xb = (short*)d_ws;                          // [MN, D] bf16 residual
  short* xin_b  = buf_xb + MN * D;                       // [MN, DI] bf16 (conv input)
  short* zb     = xin_b + MN * DI;                       // [MN, DI] bf16 (gate)
  short* y_bf   = zb + MN * DI;                          // [MN, DI] bf16
  float* u_part = (float*)(y_bf + MN * DI);              // [L, 4, 128]
  float* buf_hs = u_part + (size_t)L * 4 * 128;          // [L, 128]
  short* Wt_i   = (short*)(buf_hs + (size_t)L * 128);    // [NL, 2*DI, D] bf16
  short* Wt_o   = Wt_i + (size_t)NL * 2 * DI * D;        // [NL, D, DI]  bf16

  // prep: x bf16 copy, all weight transposes (one launch)
  prep_kernel<<<6144 + 3456 * NL, 256, 0, stream>>>(x, buf_xb, Wi, Wo, Wt_i, Wt_o);

  for (int layer = 0; layer < NL; ++layer) {
    const float* cw_l = cw + (size_t)layer * DI * 4;
    const float* cb_l = cb + (size_t)layer * DI;
    const float* A_l  = Am + (size_t)layer * L * DI * DS;
    const float* B_l  = Bm + (size_t)layer * L * DS * DI;
    const short* Wti_l = Wt_i + (size_t)layer * 2 * DI * D;
    const short* Wto_l = Wt_o + (size_t)layer * D * DI;

    // xz = x @ Wi: both halves bf16 (x_in -> xin_b, z -> zb)
    gemm_bt0<<<dim3(2 * DI / 128, MN / 128), 256, 0, stream>>>(
        buf_xb, Wti_l, xin_b, (int)MN, 2 * DI, D);

    // u partials: c-split 4-way
    conv_u_kernel<<<dim3(L, 4), 256, 0, stream>>>(xin_b, cw_l, cb_l, A_l, u_part);

    // exact parallel scan
    scan_kernel<<<128, 256, 0, stream>>>(u_part, buf_hs);

    // y = (hs @ B_l) * silu(z)
    xssm_kernel<<<dim3(L / 2, 3), 256, 0, stream>>>(buf_hs, B_l, zb, y_bf);

    // xb += y @ Wo (bf16 in-place residual; 64x128 tiles, depth-3 pipeline)
    gemm_bt1<<<dim3(D / 128, MN / 64), 256, 0, stream>>>(
        y_bf, Wto_l, buf_xb, (int)MN, D, DI);
  }

  ln_kernel<<<(int)MN, 256, 0, stream>>>(buf_xb, gam, bet, out);
}

// Round 17
// 440.707 us; speedup vs baseline: 1.0013x; 1.0013x over previous
//
#include <hip/hip_runtime.h>
#include <cstddef>
#include <cstdint>

// Problem constants
constexpr int B  = 8;
constexpr int L  = 1024;
constexpr int D  = 768;
constexpr int DI = 1536;
constexpr int DS = 16;
constexpr int NL = 2;
constexpr float DECAY   = 0.9f;
constexpr float INSCALE = 0.1f;
constexpr float LN_EPS  = 1e-5f;

typedef __attribute__((ext_vector_type(8))) short bf16x8;
typedef __attribute__((ext_vector_type(4))) float f32x4;

typedef __attribute__((address_space(3))) uint32_t       lds_u32;
typedef const __attribute__((address_space(1))) uint32_t glb_u32;

__device__ __forceinline__ float siluf(float v) { return v / (1.0f + expf(-v)); }

// f32 -> bf16 (round to nearest even)
__device__ __forceinline__ short f2bf(float f) {
  uint32_t u = __float_as_uint(f);
  u += 0x7fff + ((u >> 16) & 1);
  return (short)(u >> 16);
}
__device__ __forceinline__ float bf2f(short s) {
  return __uint_as_float(((uint32_t)(uint16_t)s) << 16);
}

__device__ __forceinline__ void load_lds16(const short* g, short* l) {
  __builtin_amdgcn_global_load_lds((glb_u32*)g, (lds_u32*)l, 16, 0, 0);
}

// ---------------- prep: x -> bf16 + weight transposes (one launch) ----------------
__global__ __launch_bounds__(256) void prep_kernel(const float* __restrict__ x,
                                                   short* __restrict__ xb,
                                                   const float* __restrict__ Wi,
                                                   const float* __restrict__ Wo,
                                                   short* __restrict__ Wt_i,
                                                   short* __restrict__ Wt_o) {
  int bid = blockIdx.x;
  if (bid < 6144) {
    int i = bid * 256 + threadIdx.x;
    float4 v = ((const float4*)x)[i];
    short4 s;
    s.x = f2bf(v.x); s.y = f2bf(v.y); s.z = f2bf(v.z); s.w = f2bf(v.w);
    ((short4*)xb)[i] = s;
    return;
  }
  bid -= 6144;
  __shared__ float t[32][33];
  const int layer = bid / 3456;
  bid %= 3456;
  const float* W; short* Wt; int K, N, bx, by;
  if (bid < 2304) {           // Wi tiles: 96 x, 24 y
    W  = Wi  + (size_t)layer * D * 2 * DI;
    Wt = Wt_i + (size_t)layer * 2 * DI * D;
    K = D; N = 2 * DI; bx = bid % 96; by = bid / 96;
  } else {                    // Wo tiles: 24 x, 48 y
    bid -= 2304;
    W  = Wo  + (size_t)layer * DI * D;
    Wt = Wt_o + (size_t)layer * D * DI;
    K = DI; N = D; bx = bid % 24; by = bid / 24;
  }
  const int n0 = bx * 32, k0 = by * 32;
  const int tx = threadIdx.x & 31, ty = threadIdx.x >> 5;
#pragma unroll
  for (int r = ty; r < 32; r += 8) t[r][tx] = W[(size_t)(k0 + r) * N + n0 + tx];
  __syncthreads();
#pragma unroll
  for (int r = ty; r < 32; r += 8) Wt[(size_t)(n0 + r) * K + k0 + tx] = f2bf(t[tx][r]);
}

// ---------------- GEMM1: 256x256 tile, 8-wave, 8-phase m201-style pipeline ----------
// C[M,N] = A[M,K] @ Bt[N,K]^T; split bf16 output (x_in / z halves).
// BK=64. LDS 128 KB: A[d][h] (d=dbuf, h=row-half 128x64) at (d*2+h)*8192 shorts,
// B[d][h] at 32768 + (d*2+h)*8192. Swizzle: byte ^= (row&7)<<4 (involution; inverse
// applied to global source since global_load_lds writes linearly - rule #21).
// Iteration processes K-tiles t0 (buf0, phases 0-3) and t0+1 (buf1, phases 4-7);
// phase q computes C-quadrant (mreps 2q,2q+1) x full K=64.
// Stage plan (1 half-tile = 2 loads/wave per phase; region freed by prior barrier):
//   ph0: A(b1,h0,t0+1)  ph1: A(b1,h1,t0+1)   [buf1.A freed by prev ph7 exit]
//   ph2: B(b0,h0,t0+2)  ph3: B(b0,h1,t0+2)   [buf0.B freed by ph0 exit]
//   ph4: A(b0,h0,t0+2)  ph5: A(b0,h1,t0+2)   [buf0.A freed by ph3 exit]
//   ph6: B(b1,h0,t0+3)  ph7: B(b1,h1,t0+3)   [buf1.B freed by ph4 exit]
// Per-wave FIFO at ph3-end: [B(b1,t1)prev x2st, A(b1,t1) x2st, B(b0,t0+2) x2st] ->
//   vmcnt(4) retires first two groups (needed ph4), leaves B(b0,t0+2) in flight.
// At ph7-end: [B(b0,t0+2), A(b0,t0+2), B(b1,t0+3)] -> vmcnt(4) retires buf0 tiles
//   (needed next ph0), leaves B(b1,t0+3). Last iteration: vmcnt(0) drains.
__global__ __launch_bounds__(512, 2) void gemm_bt0_8p(const short* __restrict__ Aop,
                                                      const short* __restrict__ Bt,
                                                      short* __restrict__ Pb,
                                                      int M, int N, int K) {
  __shared__ short lds[65536];   // 128 KB
  const int tid  = threadIdx.x;
  const int lane = tid & 63;
  const int w    = tid >> 6;     // 0..7
  const int wm   = w >> 2;       // 0..1 (M half)
  const int wn   = w & 3;        // 0..3 (N quarter)
  const int bm   = blockIdx.y * 256;
  const int bn   = blockIdx.x * 256;

  // staging source map: physical P = g*8192 + tid*16; logical Q = P ^ (((P>>7)&7)<<4)
  int srow[2], skc[2];
#pragma unroll
  for (int g = 0; g < 2; ++g) {
    const int P = g * 8192 + tid * 16;
    const int Q = P ^ (((P >> 7) & 7) << 4);
    srow[g] = Q >> 7;            // 0..127 (g=0 -> 0..63, g=1 -> 64..127)
    skc[g]  = (Q >> 4) & 7;      // 16-B chunk -> k-offset skc*8 shorts
  }

  auto stageA = [&](int d, int h, int kt) {
#pragma unroll
    for (int g = 0; g < 2; ++g)
      load_lds16(Aop + (size_t)(bm + h * 128 + srow[g]) * K + kt * 64 + skc[g] * 8,
                 &lds[(d * 2 + h) * 8192 + g * 4096 + tid * 8]);
  };
  auto stageB = [&](int d, int h, int kt) {
#pragma unroll
    for (int g = 0; g < 2; ++g)
      load_lds16(Bt + (size_t)(bn + h * 128 + srow[g]) * K + kt * 64 + skc[g] * 8,
                 &lds[32768 + (d * 2 + h) * 8192 + g * 4096 + tid * 8]);
  };

  const int fr   = lane & 15;
  const int hh16 = (lane >> 4) << 4;   // byte offset of this lane's 16B k-chunk

  auto rdA = [&](int d, int i, int ks) {
    const int r  = wm * 128 + i * 16 + fr;   // 0..255
    const int h  = r >> 7;
    const int rl = r & 127;
    int by = rl * 128 + ks * 64 + hh16;
    by ^= (rl & 7) << 4;
    return *(const bf16x8*)&lds[(d * 2 + h) * 8192 + (by >> 1)];
  };
  auto rdB = [&](int d, int j, int ks) {
    const int r  = wn * 64 + j * 16 + fr;    // 0..255
    const int h  = r >> 7;
    const int rl = r & 127;
    int by = rl * 128 + ks * 64 + hh16;
    by ^= (rl & 7) << 4;
    return *(const bf16x8*)&lds[32768 + (d * 2 + h) * 8192 + (by >> 1)];
  };

  f32x4 acc[8][4];
#pragma unroll
  for (int i = 0; i < 8; ++i)
#pragma unroll
    for (int j = 0; j < 4; ++j) acc[i][j] = (f32x4)(0.f);

  const int NTT = K / 64;   // 12 K-tiles

  // prologue: buf0 full (tile 0) + buf1.B (tile 1); buf1.A staged in iter0 ph0/1
  stageB(0, 0, 0); stageB(0, 1, 0);
  stageA(0, 0, 0); stageA(0, 1, 0);
  stageB(1, 0, 1); stageB(1, 1, 1);
  asm volatile("s_waitcnt vmcnt(4)" ::: "memory");   // buf0 landed; B(b1) in flight
  asm volatile("s_barrier" ::: "memory");

  bf16x8 bfrag[4][2], afrag[2][2];

  for (int t0 = 0; t0 < NTT; t0 += 2) {
#pragma unroll
    for (int ph = 0; ph < 8; ++ph) {
      const int d = ph >> 2;           // buffer: 0 for ph0-3 (tile t0), 1 for ph4-7
      const int q = ph & 3;            // C-quadrant (mreps 2q, 2q+1)
      // ds-reads for this phase (visibility ensured by prev phase's vmcnt+barrier)
      if (q == 0) {
#pragma unroll
        for (int j = 0; j < 4; ++j)
#pragma unroll
          for (int ks = 0; ks < 2; ++ks)
            bfrag[j][ks] = rdB(d, j, ks);
      }
#pragma unroll
      for (int ii = 0; ii < 2; ++ii)
#pragma unroll
        for (int ks = 0; ks < 2; ++ks)
          afrag[ii][ks] = rdA(d, q * 2 + ii, ks);
      // stage this phase's half-tile (region freed by an earlier exit barrier)
      switch (ph) {
        case 0: stageA(1, 0, t0 + 1); break;
        case 1: stageA(1, 1, t0 + 1); break;
        case 2: if (t0 + 2 < NTT) stageB(0, 0, t0 + 2); break;
        case 3: if (t0 + 2 < NTT) stageB(0, 1, t0 + 2); break;
        case 4: if (t0 + 2 < NTT) stageA(0, 0, t0 + 2); break;
        case 5: if (t0 + 2 < NTT) stageA(0, 1, t0 + 2); break;
        case 6: if (t0 + 3 < NTT) stageB(1, 0, t0 + 3); break;
        case 7: if (t0 + 3 < NTT) stageB(1, 1, t0 + 3); break;
      }
      asm volatile("s_barrier" ::: "memory");          // entry barrier
      __builtin_amdgcn_s_setprio(1);
#pragma unroll
      for (int ks = 0; ks < 2; ++ks)                   // K ascending -> bit-exact
#pragma unroll
        for (int ii = 0; ii < 2; ++ii)
#pragma unroll
          for (int j = 0; j < 4; ++j)
            acc[q * 2 + ii][j] = __builtin_amdgcn_mfma_f32_16x16x32_bf16(
                afrag[ii][ks], bfrag[j][ks], acc[q * 2 + ii][j], 0, 0, 0);
      __builtin_amdgcn_s_setprio(0);
      if (q == 3) {
        const bool more = (d == 0) ? (t0 + 2 < NTT) : (t0 + 3 < NTT);
        if (more) asm volatile("s_waitcnt vmcnt(4)" ::: "memory");
        else      asm volatile("s_waitcnt vmcnt(0)" ::: "memory");
      }
      asm volatile("s_barrier" ::: "memory");          // exit barrier (frees regions)
    }
  }

  // epilogue: C/D frag mapping col=lane&15, row=(lane>>4)*4+r
  const int orow = (lane >> 4) * 4;
  const int ocol = lane & 15;
#pragma unroll
  for (int i = 0; i < 8; ++i) {
#pragma unroll
    for (int r = 0; r < 4; ++r) {
      const size_t row = (size_t)(bm + wm * 128 + i * 16 + orow + r);
#pragma unroll
      for (int j = 0; j < 4; ++j) {
        const int col = bn + wn * 64 + j * 16 + ocol;
        float v = acc[i][j][r];
        if (col < DI) Pb[row * DI + col] = f2bf(v);
        else          Pb[(size_t)M * DI + row * DI + col - DI] = f2bf(v);
      }
    }
  }
}

// ---------------- GEMM2: 64x128 tile, 4-buffer depth-3 pipeline (R16) ----------
__global__ __launch_bounds__(256) void gemm_bt1(const short* __restrict__ A,
                                                const short* __restrict__ Bt,
                                                short* __restrict__ Pb,
                                                int M, int N, int K) {
  __shared__ short As[4][64 * 32];
  __shared__ short Bs[4][128 * 32];
  const int lane = threadIdx.x & 63;
  const int w    = threadIdx.x >> 6;
  const int bm   = blockIdx.y * 64;
  const int bn   = blockIdx.x * 128;

  const int lane16 = lane << 4;
  const int PA = (w << 10) + lane16;
  const int QA = PA ^ (((PA >> 7) & 3) << 4);
  const int rowA = QA >> 6;
  const int gA_  = (QA >> 4) & 3;
  const int PB0 = ((2 * w) << 10) + lane16;
  const int QB0 = PB0 ^ (((PB0 >> 7) & 3) << 4);
  const int rowB0 = QB0 >> 6;
  const int gB0_  = (QB0 >> 4) & 3;
  const int PB1 = ((2 * w + 1) << 10) + lane16;
  const int QB1 = PB1 ^ (((PB1 >> 7) & 3) << 4);
  const int rowB1 = QB1 >> 6;
  const int gB1_  = (QB1 >> 4) & 3;

  const short* gA  = A  + (size_t)(bm + rowA) * K + gA_ * 8;
  const short* gB0 = Bt + (size_t)(bn + rowB0) * K + gB0_ * 8;
  const short* gB1 = Bt + (size_t)(bn + rowB1) * K + gB1_ * 8;

  f32x4 acc[4][2];
#pragma unroll
  for (int i = 0; i < 4; ++i)
#pragma unroll
    for (int j = 0; j < 2; ++j) acc[i][j] = (f32x4)(0.f);

  const int fr = lane & 15;
  const int h8 = (lane >> 4) << 3;
  const int NT = K / 32;    // 48

  auto stage = [&](int bi, int k0) {
    load_lds16(gA  + k0, &As[bi][(size_t)w * 512]);
    load_lds16(gB0 + k0, &Bs[bi][(size_t)(2 * w) * 512]);
    load_lds16(gB1 + k0, &Bs[bi][(size_t)(2 * w + 1) * 512]);
  };
  auto compute = [&](int bi) {
    bf16x8 af[4], bfr[2];
#pragma unroll
    for (int i = 0; i < 4; ++i) {
      const int r = i * 16 + fr;
      int si = (r << 5) + h8;
      si ^= ((r >> 1) & 3) << 3;
      af[i] = *(const bf16x8*)&As[bi][si];
    }
#pragma unroll
    for (int j = 0; j < 2; ++j) {
      const int r = w * 32 + j * 16 + fr;
      int si = (r << 5) + h8;
      si ^= ((r >> 1) & 3) << 3;
      bfr[j] = *(const bf16x8*)&Bs[bi][si];
    }
#pragma unroll
    for (int i = 0; i < 4; ++i)
#pragma unroll
      for (int j = 0; j < 2; ++j)
        acc[i][j] = __builtin_amdgcn_mfma_f32_16x16x32_bf16(af[i], bfr[j], acc[i][j], 0, 0, 0);
  };

  stage(0, 0);
  stage(1, 32);
  stage(2, 64);

  for (int t = 0; t < NT; t += 4) {
#pragma unroll
    for (int q = 0; q < 4; ++q) {
      const int tt = t + q;
      if (tt + 2 < NT)      asm volatile("s_waitcnt vmcnt(6)" ::: "memory");
      else if (tt + 1 < NT) asm volatile("s_waitcnt vmcnt(3)" ::: "memory");
      else                  asm volatile("s_waitcnt vmcnt(0)" ::: "memory");
      asm volatile("s_barrier" ::: "memory");
      if (tt + 3 < NT) stage((tt + 3) & 3, (tt + 3) * 32);
      compute(q);
    }
  }

  const int orow = (lane >> 4) * 4;
  const int ocol = lane & 15;
#pragma unroll
  for (int i = 0; i < 4; ++i) {
#pragma unroll
    for (int r = 0; r < 4; ++r) {
      const size_t row = (size_t)(bm + i * 16 + orow + r);
#pragma unroll
      for (int j = 0; j < 2; ++j) {
        const int col = bn + w * 32 + j * 16 + ocol;
        float o = bf2f(Pb[row * N + col]) + acc[i][j][r];
        Pb[row * N + col] = f2bf(o);
      }
    }
  }
}

// ---------------- fused conv+SiLU -> partial u reduction, c-split 4-way ----------------
constexpr int CSL = DI / 4;   // 384 channels per slice
__global__ __launch_bounds__(256) void conv_u_kernel(const short* __restrict__ xin,  // [B*L, DI] bf16
                                                     const float* __restrict__ cw,   // [DI,4]
                                                     const float* __restrict__ cb,   // [DI]
                                                     const float* __restrict__ A_l,  // [L,DI,DS]
                                                     float* __restrict__ u_part) {   // [L,4,128]
  const int l = blockIdx.x;
  const int p = blockIdx.y;
  const int c_base = p * CSL;
  __shared__ float xs[B][CSL];        // 12 KB
  __shared__ float part[4][4][32];

  for (int i = threadIdx.x; i < B * (CSL / 4); i += 256) {
    const int b  = i / (CSL / 4);
    const int c4 = (i % (CSL / 4)) * 4;
    const int c  = c_base + c4;
    float4 q0 = *(const float4*)&cw[(c + 0) * 4];
    float4 q1 = *(const float4*)&cw[(c + 1) * 4];
    float4 q2 = *(const float4*)&cw[(c + 2) * 4];
    float4 q3 = *(const float4*)&cw[(c + 3) * 4];
    float4 acc = *(const float4*)&cb[c];
    const short* xp = xin + (size_t)b * L * DI + c;
#pragma unroll
    for (int k = 0; k < 4; ++k) {
      int lk = l - 3 + k;
      if (lk >= 0) {
        short4 xv = *(const short4*)&xp[(size_t)lk * DI];
        acc.x += (&q0.x)[k] * bf2f(xv.x);
        acc.y += (&q1.x)[k] * bf2f(xv.y);
        acc.z += (&q2.x)[k] * bf2f(xv.z);
        acc.w += (&q3.x)[k] * bf2f(xv.w);
      }
    }
    acc.x = siluf(acc.x); acc.y = siluf(acc.y);
    acc.z = siluf(acc.z); acc.w = siluf(acc.w);
    *(float4*)&xs[b][c4] = acc;
  }
  __syncthreads();

  const int s4 = threadIdx.x & 3;
  const int cg = threadIdx.x >> 2;   // 0..63
  const float* Ap = A_l + (size_t)l * DI * DS + s4 * 4;

  float4 acc[B];
#pragma unroll
  for (int b = 0; b < B; ++b) acc[b] = make_float4(0.f, 0.f, 0.f, 0.f);

#pragma unroll
  for (int c0 = 0; c0 < CSL; c0 += 64) {
    const int cl = c0 + cg;
    float4 a4 = *(const float4*)&Ap[(size_t)(c_base + cl) * DS];
#pragma unroll
    for (int b = 0; b < B; ++b) {
      float xv = xs[b][cl];
      acc[b].x += xv * a4.x; acc[b].y += xv * a4.y;
      acc[b].z += xv * a4.z; acc[b].w += xv * a4.w;
    }
  }

#pragma unroll
  for (int off = 32; off >= 4; off >>= 1) {
#pragma unroll
    for (int b = 0; b < B; ++b) {
      acc[b].x += __shfl_down(acc[b].x, off, 64);
      acc[b].y += __shfl_down(acc[b].y, off, 64);
      acc[b].z += __shfl_down(acc[b].z, off, 64);
      acc[b].w += __shfl_down(acc[b].w, off, 64);
    }
  }
  const int wv = threadIdx.x >> 6, lane = threadIdx.x & 63;
  if (lane < 4) {
#pragma unroll
    for (int b = 0; b < B; ++b) {
      part[wv][lane][b * 4 + 0] = acc[b].x;
      part[wv][lane][b * 4 + 1] = acc[b].y;
      part[wv][lane][b * 4 + 2] = acc[b].z;
      part[wv][lane][b * 4 + 3] = acc[b].w;
    }
  }
  __syncthreads();
  if (threadIdx.x < 128) {
    const int o  = threadIdx.x;           // b*16 + s4*4 + jj
    const int b  = o >> 4;
    const int ss = (o >> 2) & 3;
    const int jj = o & 3;
    float s = part[0][ss][b * 4 + jj] + part[1][ss][b * 4 + jj] +
              part[2][ss][b * 4 + jj] + part[3][ss][b * 4 + jj];
    u_part[((size_t)l * 4 + p) * 128 + o] = INSCALE * s;
  }
}

// ---------------- exact parallel scan (per-stream Hillis-Steele) ----------------
__global__ __launch_bounds__(256) void scan_kernel(const float* __restrict__ u_part, // [L,4,128]
                                                   float* __restrict__ hs) {         // [L,128]
  const int t = blockIdx.x;
  const int i = threadIdx.x;
  __shared__ float csc[256];

  float v[4];
#pragma unroll
  for (int j = 0; j < 4; ++j) {
    const float* up = u_part + ((size_t)(4 * i + j) * 4) * 128 + t;
    v[j] = (up[0] + up[128]) + (up[256] + up[384]);
  }
  const float p0 = v[0];
  const float p1 = p0 * DECAY + v[1];
  const float p2 = p1 * DECAY + v[2];
  const float p3 = p2 * DECAY + v[3];

  csc[i] = p3;
  __syncthreads();
  float f = DECAY * DECAY * DECAY * DECAY;   // 0.9^4
  for (int d = 1; d < 256; d <<= 1) {
    float add = (i >= d) ? csc[i - d] : 0.f;
    __syncthreads();
    csc[i] += add * f;
    __syncthreads();
    f *= f;
  }
  const float H = (i > 0) ? csc[i - 1] : 0.f;  // h_{4i-1}

  const float a1 = DECAY, a2 = DECAY * DECAY, a3 = a2 * DECAY, a4 = a2 * a2;
  float* hp = hs + (size_t)(4 * i) * 128 + t;
  hp[0]   = p0 + H * a1;
  hp[128] = p1 + H * a2;
  hp[256] = p2 + H * a3;
  hp[384] = p3 + H * a4;
}

// ---------------- xssm: y = (hs @ Bm) * silu(z), streaming ----------------
__global__ __launch_bounds__(256) void xssm_kernel(const float* __restrict__ hs,   // [L,128]
                                                   const float* __restrict__ B_l,  // [L,DS,DI]
                                                   const short* __restrict__ zb,   // [B*L,DI] bf16
                                                   short* __restrict__ y) {        // [B*L,DI] bf16
  const int l0 = blockIdx.x * 2;
  const int cb = blockIdx.y * (DI / 3);
  __shared__ float hsl[2][128];
  const int t = threadIdx.x;
  hsl[t >> 7][t & 127] = hs[(size_t)(l0 + (t >> 7)) * 128 + (t & 127)];
  __syncthreads();

  const int li = t >> 7;
  const int l  = l0 + li;
  const int c  = cb + (t & 127) * 4;
  const float* Bp = B_l + (size_t)l * DS * DI + c;

  float4 acc[B];
#pragma unroll
  for (int b = 0; b < B; ++b) acc[b] = make_float4(0.f, 0.f, 0.f, 0.f);
#pragma unroll
  for (int s = 0; s < DS; ++s) {
    float4 bv = *(const float4*)&Bp[(size_t)s * DI];
#pragma unroll
    for (int b = 0; b < B; ++b) {
      float hv = hsl[li][b * DS + s];
      acc[b].x += hv * bv.x; acc[b].y += hv * bv.y;
      acc[b].z += hv * bv.z; acc[b].w += hv * bv.w;
    }
  }
#pragma unroll
  for (int b = 0; b < B; ++b) {
    short4 zs = *(const short4*)&zb[((size_t)b * L + l) * DI + c];
    short4 o;
    o.x = f2bf(acc[b].x * siluf(bf2f(zs.x)));
    o.y = f2bf(acc[b].y * siluf(bf2f(zs.y)));
    o.z = f2bf(acc[b].z * siluf(bf2f(zs.z)));
    o.w = f2bf(acc[b].w * siluf(bf2f(zs.w)));
    *(short4*)&y[((size_t)b * L + l) * DI + c] = o;
  }
}

// ---------------- LayerNorm over D (bf16 input) ----------------
__global__ __launch_bounds__(256) void ln_kernel(const short* __restrict__ x,
                                                 const float* __restrict__ gam,
                                                 const float* __restrict__ bet,
                                                 float* __restrict__ out) {
  const int row = blockIdx.x;
  const int t = threadIdx.x;
  const short* xr = x + (size_t)row * D;
  float v0 = bf2f(xr[t]), v1 = bf2f(xr[t + 256]), v2 = bf2f(xr[t + 512]);
  float s = v0 + v1 + v2;
  __shared__ float red[4], red2[4];
  const int wid = t >> 6, lane = t & 63;
#pragma unroll
  for (int off = 32; off > 0; off >>= 1) s += __shfl_down(s, off, 64);
  if (lane == 0) red[wid] = s;
  __syncthreads();
  float mu = (red[0] + red[1] + red[2] + red[3]) * (1.0f / D);
  float d0 = v0 - mu, d1 = v1 - mu, d2 = v2 - mu;
  float q = d0 * d0 + d1 * d1 + d2 * d2;
#pragma unroll
  for (int off = 32; off > 0; off >>= 1) q += __shfl_down(q, off, 64);
  if (lane == 0) red2[wid] = q;
  __syncthreads();
  float var = (red2[0] + red2[1] + red2[2] + red2[3]) * (1.0f / D);
  float rstd = rsqrtf(var + LN_EPS);
  size_t base = (size_t)row * D;
  out[base + t]       = d0 * rstd * gam[t]       + bet[t];
  out[base + t + 256] = d1 * rstd * gam[t + 256] + bet[t + 256];
  out[base + t + 512] = d2 * rstd * gam[t + 512] + bet[t + 512];
}

extern "C" void kernel_launch(void* const* d_in, const int* in_sizes, int n_in,
                              void* d_out, int out_size, void* d_ws, size_t ws_size,
                              hipStream_t stream) {
  (void)in_sizes; (void)n_in; (void)out_size; (void)ws_size;
  const float* x   = (const float*)d_in[0];
  const float* Wi  = (const float*)d_in[1];
  const float* cw  = (const float*)d_in[2];
  const float* cb  = (const float*)d_in[3];
  const float* Wo  = (const float*)d_in[4];
  const float* gam = (const float*)d_in[5];
  const float* bet = (const float*)d_in[6];
  const float* Am  = (const float*)d_in[7];
  const float* Bm  = (const float*)d_in[8];
  float* out = (float*)d_out;

  const size_t MN = (size_t)B * L;  // 8192

  short* buf_xb = (short*)d_ws;                          // [MN, D] bf16 residual
  short* xin_b  = buf_xb + MN * D;                       // [MN, DI] bf16 (conv input)
  short* zb     = xin_b + MN * DI;                       // [MN, DI] bf16 (gate)
  short* y_bf   = zb + MN * DI;                          // [MN, DI] bf16
  float* u_part = (float*)(y_bf + MN * DI);              // [L, 4, 128]
  float* buf_hs = u_part + (size_t)L * 4 * 128;          // [L, 128]
  short* Wt_i   = (short*)(buf_hs + (size_t)L * 128);    // [NL, 2*DI, D] bf16
  short* Wt_o   = Wt_i + (size_t)NL * 2 * DI * D;        // [NL, D, DI]  bf16

  // prep: x bf16 copy, all weight transposes (one launch)
  prep_kernel<<<6144 + 3456 * NL, 256, 0, stream>>>(x, buf_xb, Wi, Wo, Wt_i, Wt_o);

  for (int layer = 0; layer < NL; ++layer) {
    const float* cw_l = cw + (size_t)layer * DI * 4;
    const float* cb_l = cb + (size_t)layer * DI;
    const float* A_l  = Am + (size_t)layer * L * DI * DS;
    const float* B_l  = Bm + (size_t)layer * L * DS * DI;
    const short* Wti_l = Wt_i + (size_t)layer * 2 * DI * D;
    const short* Wto_l = Wt_o + (size_t)layer * D * DI;

    // xz = x @ Wi: 256^2 8-phase pipeline; x_in -> xin_b, z -> zb (both bf16)
    gemm_bt0_8p<<<dim3(2 * DI / 256, MN / 256), 512, 0, stream>>>(
        buf_xb, Wti_l, xin_b, (int)MN, 2 * DI, D);

    // u partials: c-split 4-way
    conv_u_kernel<<<dim3(L, 4), 256, 0, stream>>>(xin_b, cw_l, cb_l, A_l, u_part);

    // exact parallel scan
    scan_kernel<<<128, 256, 0, stream>>>(u_part, buf_hs);

    // y = (hs @ B_l) * silu(z)
    xssm_kernel<<<dim3(L / 2, 3), 256, 0, stream>>>(buf_hs, B_l, zb, y_bf);

    // xb += y @ Wo (bf16 in-place residual; 64x128 tiles, depth-3 pipeline)
    gemm_bt1<<<dim3(D / 128, MN / 64), 256, 0, stream>>>(
        y_bf, Wto_l, buf_xb, (int)MN, D, DI);
  }

  ln_kernel<<<(int)MN, 256, 0, stream>>>(buf_xb, gam, bet, out);
}